// Round 1
// baseline (3895.671 us; speedup 1.0000x reference)
//
#include <hip/hip_runtime.h>
#include <hip/hip_bf16.h>
#include <math.h>

#define F_IN 200
#define HDIM 64
#define NPG  400
#define EPG  6400
#define KSEL 200   // NPG/2

// ---------------- pack [K,64]|[K,64] -> [K,128] ----------------
__global__ void pack_w(const float* __restrict__ Wl, const float* __restrict__ Wr,
                       float* __restrict__ Wc, int K) {
    int i = blockIdx.x * blockDim.x + threadIdx.x;
    if (i >= K * 128) return;
    int k = i >> 7, c = i & 127;
    Wc[i] = (c < 64) ? Wl[k * 64 + c] : Wr[k * 64 + (c - 64)];
}

// ---------------- GEMM: O[N,128] = X[N,K] @ W[K,128] ----------------
// block = 256 threads, 64 rows/block. X row stride = ldx (200 for layer1 input,
// 128 for activations stored as column-halves of a [N,128] buffer).
template <int K>
__global__ __launch_bounds__(256) void gemm128(const float* __restrict__ X, int ldx,
                                               const float* __restrict__ W,
                                               float* __restrict__ O) {
    __shared__ float xs[64][K];
    const int rowbase = blockIdx.x * 64;
    const int tid = threadIdx.x;
    for (int idx = tid; idx < 64 * K; idx += 256) {
        int r = idx / K, c = idx - r * K;
        xs[r][c] = X[(size_t)(rowbase + r) * ldx + c];
    }
    __syncthreads();
    const int c4 = (tid & 31) * 4;
    const int rb = (tid >> 5) * 8;
    float acc[8][4];
#pragma unroll
    for (int r = 0; r < 8; r++)
#pragma unroll
        for (int j = 0; j < 4; j++) acc[r][j] = 0.f;

    for (int k = 0; k < K; k += 4) {
        float4 xv[8];
#pragma unroll
        for (int r = 0; r < 8; r++) xv[r] = *(const float4*)&xs[rb + r][k];
#pragma unroll
        for (int kk = 0; kk < 4; kk++) {
            float4 w = *(const float4*)&W[(size_t)(k + kk) * 128 + c4];
#pragma unroll
            for (int r = 0; r < 8; r++) {
                float xvv = (kk == 0) ? xv[r].x : (kk == 1) ? xv[r].y : (kk == 2) ? xv[r].z : xv[r].w;
                acc[r][0] += xvv * w.x;
                acc[r][1] += xvv * w.y;
                acc[r][2] += xvv * w.z;
                acc[r][3] += xvv * w.w;
            }
        }
    }
#pragma unroll
    for (int r = 0; r < 8; r++) {
        float4 v = make_float4(acc[r][0], acc[r][1], acc[r][2], acc[r][3]);
        *(float4*)&O[(size_t)(rowbase + rb + r) * 128 + c4] = v;
    }
}

// ---------------- per-graph aggregate + combine ----------------
// A[N,128]: cols 0..63 = y = h@Wl, cols 64..127 = z = h@Wr.
// out = relu(segsum(y[src])*invdeg + b + z) (+ resid). One block per graph.
__global__ __launch_bounds__(256) void agg_combine(
    const float* __restrict__ A,
    const int* __restrict__ esrc, const int* __restrict__ edst,
    const float* __restrict__ bias,
    const float* __restrict__ resid, int rescol,   // resid may be null
    float* __restrict__ Xout, int outcol,          // write Xout[row*128+outcol+d]
    float* __restrict__ invdeg, int computeDeg)
{
    __shared__ float agg[NPG * 64];
    __shared__ float ldeg[NPG];
    const int g = blockIdx.x, tid = threadIdx.x;
    for (int i = tid; i < NPG * 64; i += 256) agg[i] = 0.f;
    if (computeDeg)
        for (int i = tid; i < NPG; i += 256) ldeg[i] = 0.f;
    __syncthreads();

    const int ebase = g * EPG;
    const int nodebase = g * NPG;
    const int lane = tid & 63;
    const int wv = tid >> 6;
    for (int e = wv; e < EPG; e += 4) {
        int src = esrc[ebase + e];
        int ld = edst[ebase + e] - nodebase;
        float v = A[(size_t)src * 128 + lane];
        atomicAdd(&agg[ld * 64 + lane], v);
        if (computeDeg && lane == 0) atomicAdd(&ldeg[ld], 1.f);
    }
    __syncthreads();

    if (computeDeg) {
        for (int i = tid; i < NPG; i += 256)
            invdeg[nodebase + i] = 1.f / fmaxf(ldeg[i], 1.f);
    }
    for (int i = tid; i < NPG * 64; i += 256) {
        int node = i >> 6, d = i & 63;
        float inv = computeDeg ? (1.f / fmaxf(ldeg[node], 1.f)) : invdeg[nodebase + node];
        float v = agg[i] * inv + bias[d] + A[(size_t)(nodebase + node) * 128 + 64 + d];
        v = fmaxf(v, 0.f);
        if (resid) v += resid[(size_t)(nodebase + node) * 128 + rescol + d];
        Xout[(size_t)(nodebase + node) * 128 + outcol + d] = v;
    }
}

// ---------------- per-graph score + top-k + pool + classifier ----------------
__global__ __launch_bounds__(256) void score_pool(
    const float* __restrict__ X3, int x3col,       // stride 128
    const int* __restrict__ esrc, const int* __restrict__ edst,
    const float* __restrict__ Wpr, const float* __restrict__ bpr,
    const float* __restrict__ Wpo,
    const float* __restrict__ Wlin, const float* __restrict__ blin,
    float* __restrict__ out)
{
    __shared__ float t0[NPG], s[NPG], w[NPG];
    __shared__ float wpr[64], wpo[64];
    __shared__ float pp[4 * 64];
    __shared__ float pooled[64];
    __shared__ float lg[2];
    const int g = blockIdx.x, tid = threadIdx.x;
    if (tid < 64) { wpr[tid] = Wpr[tid]; wpo[tid] = Wpo[tid]; }
    __syncthreads();

    const int nodebase = g * NPG;
    for (int i = tid; i < NPG; i += 256) {
        const float* xr = &X3[(size_t)(nodebase + i) * 128 + x3col];
        float a0 = 0.f, a1 = 0.f;
        for (int d = 0; d < 64; d++) { float x = xr[d]; a0 += x * wpr[d]; a1 += x * wpo[d]; }
        t0[i] = a0;
        s[i] = bpr[0] + a1;
    }
    __syncthreads();
    const int ebase = g * EPG;
    for (int e = tid; e < EPG; e += 256) {
        int ls = esrc[ebase + e] - nodebase;
        int ld = edst[ebase + e] - nodebase;
        atomicAdd(&s[ld], t0[ls]);
    }
    __syncthreads();
    // stable top-k selection by counting (matches lax.top_k tie-breaking)
    for (int i = tid; i < NPG; i += 256) {
        float si = s[i];
        int cnt = 0;
        for (int j = 0; j < NPG; j++) {
            float sj = s[j];
            cnt += (sj > si) || (sj == si && j < i);
        }
        w[i] = (cnt < KSEL) ? tanhf(si) * (1.f / KSEL) : 0.f;
    }
    __syncthreads();
    const int d = tid & 63, part = tid >> 6;
    float acc = 0.f;
    for (int i = part * 100; i < part * 100 + 100; i++)
        acc += w[i] * X3[(size_t)(nodebase + i) * 128 + x3col + d];
    pp[part * 64 + d] = acc;
    __syncthreads();
    if (tid < 64) pooled[tid] = pp[tid] + pp[64 + tid] + pp[128 + tid] + pp[192 + tid];
    __syncthreads();
    if (tid < 2) {
        float l = blin[tid];
        for (int dd = 0; dd < 64; dd++) l += pooled[dd] * Wlin[dd * 2 + tid];
        lg[tid] = l;
    }
    __syncthreads();
    if (tid < 2) {
        float m = fmaxf(lg[0], lg[1]);
        float lse = m + logf(expf(lg[0] - m) + expf(lg[1] - m));
        out[g * 2 + tid] = lg[tid] - lse;
    }
}

extern "C" void kernel_launch(void* const* d_in, const int* in_sizes, int n_in,
                              void* d_out, int out_size, void* d_ws, size_t ws_size,
                              hipStream_t stream) {
    const float* x    = (const float*)d_in[0];
    const int*   eidx = (const int*)d_in[1];
    const float* W1l  = (const float*)d_in[3];
    const float* W1r  = (const float*)d_in[4];
    const float* b1   = (const float*)d_in[5];
    const float* W2l  = (const float*)d_in[6];
    const float* W2r  = (const float*)d_in[7];
    const float* b2   = (const float*)d_in[8];
    const float* W3l  = (const float*)d_in[9];
    const float* W3r  = (const float*)d_in[10];
    const float* b3   = (const float*)d_in[11];
    const float* Wpr  = (const float*)d_in[12];
    const float* bpr  = (const float*)d_in[13];
    const float* Wpo  = (const float*)d_in[14];
    const float* Wlin = (const float*)d_in[15];
    const float* blin = (const float*)d_in[16];

    const int N = in_sizes[0] / F_IN;       // 204800
    const int E = in_sizes[1] / 2;          // 3276800
    const int B = N / NPG;                  // 512
    const int* esrc = eidx;
    const int* edst = eidx + E;

    float* ws = (float*)d_ws;
    float* A      = ws;                                  // [N,128] yz buffer
    float* Bb     = A + (size_t)N * 128;                 // [N,128] activations (col halves)
    float* invdeg = Bb + (size_t)N * 128;                // [N]
    float* Wc1    = invdeg + N;                          // [200,128]
    float* Wc2    = Wc1 + 200 * 128;                     // [64,128]
    float* Wc3    = Wc2 + 64 * 128;                      // [64,128]

    pack_w<<<(200 * 128 + 255) / 256, 256, 0, stream>>>(W1l, W1r, Wc1, 200);
    pack_w<<<(64 * 128 + 255) / 256, 256, 0, stream>>>(W2l, W2r, Wc2, 64);
    pack_w<<<(64 * 128 + 255) / 256, 256, 0, stream>>>(W3l, W3r, Wc3, 64);

    // layer 1: yz = x @ [W1l|W1r]; x1 -> Bb cols 0..63 (computes invdeg)
    gemm128<200><<<N / 64, 256, 0, stream>>>(x, F_IN, Wc1, A);
    agg_combine<<<B, 256, 0, stream>>>(A, esrc, edst, b1, nullptr, 0, Bb, 0, invdeg, 1);

    // layer 2: yz = x1 @ [W2l|W2r]; x2 = relu(...)+x1 -> Bb cols 64..127
    gemm128<64><<<N / 64, 256, 0, stream>>>(Bb, 128, Wc2, A);
    agg_combine<<<B, 256, 0, stream>>>(A, esrc, edst, b2, Bb, 0, Bb, 64, invdeg, 0);

    // layer 3: yz = x2 @ [W3l|W3r]; x3 = relu(...)+x2 -> Bb cols 0..63
    gemm128<64><<<N / 64, 256, 0, stream>>>(Bb + 64, 128, Wc3, A);
    agg_combine<<<B, 256, 0, stream>>>(A, esrc, edst, b3, Bb, 64, Bb, 0, invdeg, 0);

    // score + top-k + pool + classifier
    score_pool<<<B, 256, 0, stream>>>(Bb, 0, esrc, edst, Wpr, bpr, Wpo, Wlin, blin,
                                      (float*)d_out);
}

// Round 2
// 1014.773 us; speedup vs baseline: 3.8390x; 3.8390x over previous
//
#include <hip/hip_runtime.h>
#include <hip/hip_bf16.h>
#include <math.h>

#define F_IN 200
#define HDIM 64
#define NPG  400
#define EPG  6400
#define KSEL 200   // NPG/2

// ---------------- pack [K,64]|[K,64] -> [K,128] ----------------
__global__ void pack_w(const float* __restrict__ Wl, const float* __restrict__ Wr,
                       float* __restrict__ Wc, int K) {
    int i = blockIdx.x * blockDim.x + threadIdx.x;
    if (i >= K * 128) return;
    int k = i >> 7, c = i & 127;
    Wc[i] = (c < 64) ? Wl[k * 64 + c] : Wr[k * 64 + (c - 64)];
}

// ---------------- GEMM: O[N,128] = X[N,K] @ W[K,128] ----------------
template <int K>
__global__ __launch_bounds__(256) void gemm128(const float* __restrict__ X, int ldx,
                                               const float* __restrict__ W,
                                               float* __restrict__ O) {
    __shared__ float xs[64][K];
    const int rowbase = blockIdx.x * 64;
    const int tid = threadIdx.x;
    for (int idx = tid; idx < 64 * K; idx += 256) {
        int r = idx / K, c = idx - r * K;
        xs[r][c] = X[(size_t)(rowbase + r) * ldx + c];
    }
    __syncthreads();
    const int c4 = (tid & 31) * 4;
    const int rb = (tid >> 5) * 8;
    float acc[8][4];
#pragma unroll
    for (int r = 0; r < 8; r++)
#pragma unroll
        for (int j = 0; j < 4; j++) acc[r][j] = 0.f;

    for (int k = 0; k < K; k += 4) {
        float4 xv[8];
#pragma unroll
        for (int r = 0; r < 8; r++) xv[r] = *(const float4*)&xs[rb + r][k];
#pragma unroll
        for (int kk = 0; kk < 4; kk++) {
            float4 w = *(const float4*)&W[(size_t)(k + kk) * 128 + c4];
#pragma unroll
            for (int r = 0; r < 8; r++) {
                float xvv = (kk == 0) ? xv[r].x : (kk == 1) ? xv[r].y : (kk == 2) ? xv[r].z : xv[r].w;
                acc[r][0] += xvv * w.x;
                acc[r][1] += xvv * w.y;
                acc[r][2] += xvv * w.z;
                acc[r][3] += xvv * w.w;
            }
        }
    }
#pragma unroll
    for (int r = 0; r < 8; r++) {
        float4 v = make_float4(acc[r][0], acc[r][1], acc[r][2], acc[r][3]);
        *(float4*)&O[(size_t)(rowbase + rb + r) * 128 + c4] = v;
    }
}

// ---------------- CSR build: one block per graph ----------------
// csr_src[ebase..ebase+EPG): src indices (global) grouped by local dst.
// rowptr[node] = global offset of node's in-edge list; degs[node] = count.
__global__ __launch_bounds__(256) void csr_build(
    const int* __restrict__ esrc, const int* __restrict__ edst,
    int* __restrict__ csr_src, int* __restrict__ rowptr,
    int* __restrict__ degs, float* __restrict__ invdeg)
{
    __shared__ int cnt[NPG];
    __shared__ int off[NPG];
    __shared__ int cur[NPG];
    const int g = blockIdx.x, tid = threadIdx.x;
    const int ebase = g * EPG, nodebase = g * NPG;
    for (int i = tid; i < NPG; i += 256) cnt[i] = 0;
    __syncthreads();
    for (int e = tid; e < EPG; e += 256)
        atomicAdd(&cnt[edst[ebase + e] - nodebase], 1);
    __syncthreads();
    if (tid == 0) {
        int run = 0;
        for (int i = 0; i < NPG; i++) { off[i] = run; run += cnt[i]; }
    }
    __syncthreads();
    for (int i = tid; i < NPG; i += 256) {
        cur[i] = off[i];
        rowptr[nodebase + i] = ebase + off[i];
        degs[nodebase + i] = cnt[i];
        invdeg[nodebase + i] = 1.f / fmaxf((float)cnt[i], 1.f);
    }
    __syncthreads();
    for (int e = tid; e < EPG; e += 256) {
        int ld = edst[ebase + e] - nodebase;
        int p = atomicAdd(&cur[ld], 1);
        csr_src[ebase + p] = esrc[ebase + e];
    }
}

// ---------------- aggregate+combine via CSR: one wave per node ----------------
// A[N,128]: cols 0..63 = y = h@Wl, cols 64..127 = z = h@Wr.
// out = relu(sum_in(y[src])*invdeg + b + z) (+ resid)
__global__ __launch_bounds__(256) void agg_csr(
    const float* __restrict__ A,
    const int* __restrict__ csr_src, const int* __restrict__ rowptr,
    const int* __restrict__ degs, const float* __restrict__ invdeg,
    const float* __restrict__ bias,
    const float* __restrict__ resid, int rescol,
    float* __restrict__ Xout, int outcol)
{
    const int node = blockIdx.x * 4 + (threadIdx.x >> 6);
    const int lane = threadIdx.x & 63;
    const int start = rowptr[node];
    const int dg = degs[node];
    float acc = 0.f;
    for (int j0 = 0; j0 < dg; j0 += 64) {
        int mys = (j0 + lane < dg) ? csr_src[start + j0 + lane] : 0;
        int m = min(64, dg - j0);
        for (int j = 0; j < m; j++) {
            int s = __shfl(mys, j);
            acc += A[(size_t)s * 128 + lane];
        }
    }
    float v = acc * invdeg[node] + bias[lane] + A[(size_t)node * 128 + 64 + lane];
    v = fmaxf(v, 0.f);
    if (resid) v += resid[(size_t)node * 128 + rescol + lane];
    Xout[(size_t)node * 128 + outcol + lane] = v;
}

// ---------------- per-graph score + top-k + pool + classifier ----------------
__global__ __launch_bounds__(256) void score_pool(
    const float* __restrict__ X3, int x3col,       // stride 128
    const int* __restrict__ esrc, const int* __restrict__ edst,
    const float* __restrict__ Wpr, const float* __restrict__ bpr,
    const float* __restrict__ Wpo,
    const float* __restrict__ Wlin, const float* __restrict__ blin,
    float* __restrict__ out)
{
    __shared__ float t0[NPG], s[NPG], w[NPG];
    __shared__ float wpr[64], wpo[64];
    __shared__ float pp[4 * 64];
    __shared__ float pooled[64];
    __shared__ float lg[2];
    const int g = blockIdx.x, tid = threadIdx.x;
    if (tid < 64) { wpr[tid] = Wpr[tid]; wpo[tid] = Wpo[tid]; }
    __syncthreads();

    const int nodebase = g * NPG;
    for (int i = tid; i < NPG; i += 256) {
        const float* xr = &X3[(size_t)(nodebase + i) * 128 + x3col];
        float a0 = 0.f, a1 = 0.f;
        for (int d = 0; d < 64; d++) { float x = xr[d]; a0 += x * wpr[d]; a1 += x * wpo[d]; }
        t0[i] = a0;
        s[i] = bpr[0] + a1;
    }
    __syncthreads();
    const int ebase = g * EPG;
    for (int e = tid; e < EPG; e += 256) {
        int ls = esrc[ebase + e] - nodebase;
        int ld = edst[ebase + e] - nodebase;
        atomicAdd(&s[ld], t0[ls]);
    }
    __syncthreads();
    // stable top-k selection by counting (matches lax.top_k tie-breaking)
    for (int i = tid; i < NPG; i += 256) {
        float si = s[i];
        int cnt = 0;
        for (int j = 0; j < NPG; j++) {
            float sj = s[j];
            cnt += (sj > si) || (sj == si && j < i);
        }
        w[i] = (cnt < KSEL) ? tanhf(si) * (1.f / KSEL) : 0.f;
    }
    __syncthreads();
    const int d = tid & 63, part = tid >> 6;
    float acc = 0.f;
    for (int i = part * 100; i < part * 100 + 100; i++)
        acc += w[i] * X3[(size_t)(nodebase + i) * 128 + x3col + d];
    pp[part * 64 + d] = acc;
    __syncthreads();
    if (tid < 64) pooled[tid] = pp[tid] + pp[64 + tid] + pp[128 + tid] + pp[192 + tid];
    __syncthreads();
    if (tid < 2) {
        float l = blin[tid];
        for (int dd = 0; dd < 64; dd++) l += pooled[dd] * Wlin[dd * 2 + tid];
        lg[tid] = l;
    }
    __syncthreads();
    if (tid < 2) {
        float m = fmaxf(lg[0], lg[1]);
        float lse = m + logf(expf(lg[0] - m) + expf(lg[1] - m));
        out[g * 2 + tid] = lg[tid] - lse;
    }
}

extern "C" void kernel_launch(void* const* d_in, const int* in_sizes, int n_in,
                              void* d_out, int out_size, void* d_ws, size_t ws_size,
                              hipStream_t stream) {
    const float* x    = (const float*)d_in[0];
    const int*   eidx = (const int*)d_in[1];
    const float* W1l  = (const float*)d_in[3];
    const float* W1r  = (const float*)d_in[4];
    const float* b1   = (const float*)d_in[5];
    const float* W2l  = (const float*)d_in[6];
    const float* W2r  = (const float*)d_in[7];
    const float* b2   = (const float*)d_in[8];
    const float* W3l  = (const float*)d_in[9];
    const float* W3r  = (const float*)d_in[10];
    const float* b3   = (const float*)d_in[11];
    const float* Wpr  = (const float*)d_in[12];
    const float* bpr  = (const float*)d_in[13];
    const float* Wpo  = (const float*)d_in[14];
    const float* Wlin = (const float*)d_in[15];
    const float* blin = (const float*)d_in[16];

    const int N = in_sizes[0] / F_IN;       // 204800
    const int E = in_sizes[1] / 2;          // 3276800
    const int B = N / NPG;                  // 512
    const int* esrc = eidx;
    const int* edst = eidx + E;

    float* ws = (float*)d_ws;
    float* A      = ws;                                  // [N,128] yz buffer
    float* Bb     = A + (size_t)N * 128;                 // [N,128] activations (col halves)
    float* invdeg = Bb + (size_t)N * 128;                // [N]
    float* Wc1    = invdeg + N;                          // [200,128]
    float* Wc2    = Wc1 + 200 * 128;                     // [64,128]
    float* Wc3    = Wc2 + 64 * 128;                      // [64,128]
    int*   csr    = (int*)(Wc3 + 64 * 128);              // [E]
    int*   rowptr = csr + E;                             // [N]
    int*   degs   = rowptr + N;                          // [N]

    pack_w<<<(200 * 128 + 255) / 256, 256, 0, stream>>>(W1l, W1r, Wc1, 200);
    pack_w<<<(64 * 128 + 255) / 256, 256, 0, stream>>>(W2l, W2r, Wc2, 64);
    pack_w<<<(64 * 128 + 255) / 256, 256, 0, stream>>>(W3l, W3r, Wc3, 64);

    // CSR once (shared by all 3 layers)
    csr_build<<<B, 256, 0, stream>>>(esrc, edst, csr, rowptr, degs, invdeg);

    // layer 1: yz = x @ [W1l|W1r]; x1 -> Bb cols 0..63
    gemm128<200><<<N / 64, 256, 0, stream>>>(x, F_IN, Wc1, A);
    agg_csr<<<N / 4, 256, 0, stream>>>(A, csr, rowptr, degs, invdeg, b1,
                                       nullptr, 0, Bb, 0);

    // layer 2: yz = x1 @ [W2l|W2r]; x2 = relu(...)+x1 -> Bb cols 64..127
    gemm128<64><<<N / 64, 256, 0, stream>>>(Bb, 128, Wc2, A);
    agg_csr<<<N / 4, 256, 0, stream>>>(A, csr, rowptr, degs, invdeg, b2,
                                       Bb, 0, Bb, 64);

    // layer 3: yz = x2 @ [W3l|W3r]; x3 = relu(...)+x2 -> Bb cols 0..63
    gemm128<64><<<N / 64, 256, 0, stream>>>(Bb + 64, 128, Wc3, A);
    agg_csr<<<N / 4, 256, 0, stream>>>(A, csr, rowptr, degs, invdeg, b3,
                                       Bb, 64, Bb, 0);

    // score + top-k + pool + classifier
    score_pool<<<B, 256, 0, stream>>>(Bb, 0, esrc, edst, Wpr, bpr, Wpo, Wlin, blin,
                                      (float*)d_out);
}

// Round 3
// 651.464 us; speedup vs baseline: 5.9799x; 1.5577x over previous
//
#include <hip/hip_runtime.h>
#include <hip/hip_bf16.h>
#include <math.h>

#define F_IN 200
#define HDIM 64
#define NPG  400
#define EPG  6400
#define KSEL 200   // NPG/2

// ---------------- pack [K,64]|[K,64] -> [K,128] ----------------
__global__ void pack_w(const float* __restrict__ Wl, const float* __restrict__ Wr,
                       float* __restrict__ Wc, int K) {
    int i = blockIdx.x * blockDim.x + threadIdx.x;
    if (i >= K * 128) return;
    int k = i >> 7, c = i & 127;
    Wc[i] = (c < 64) ? Wl[k * 64 + c] : Wr[k * 64 + (c - 64)];
}

// ---------------- GEMM: O[N,128] = X[N,K] @ W[K,128] ----------------
template <int K>
__global__ __launch_bounds__(256) void gemm128(const float* __restrict__ X, int ldx,
                                               const float* __restrict__ W,
                                               float* __restrict__ O) {
    __shared__ float xs[64][K];
    const int rowbase = blockIdx.x * 64;
    const int tid = threadIdx.x;
    for (int idx = tid; idx < 64 * K; idx += 256) {
        int r = idx / K, c = idx - r * K;
        xs[r][c] = X[(size_t)(rowbase + r) * ldx + c];
    }
    __syncthreads();
    const int c4 = (tid & 31) * 4;
    const int rb = (tid >> 5) * 8;
    float acc[8][4];
#pragma unroll
    for (int r = 0; r < 8; r++)
#pragma unroll
        for (int j = 0; j < 4; j++) acc[r][j] = 0.f;

    for (int k = 0; k < K; k += 4) {
        float4 xv[8];
#pragma unroll
        for (int r = 0; r < 8; r++) xv[r] = *(const float4*)&xs[rb + r][k];
#pragma unroll
        for (int kk = 0; kk < 4; kk++) {
            float4 w = *(const float4*)&W[(size_t)(k + kk) * 128 + c4];
#pragma unroll
            for (int r = 0; r < 8; r++) {
                float xvv = (kk == 0) ? xv[r].x : (kk == 1) ? xv[r].y : (kk == 2) ? xv[r].z : xv[r].w;
                acc[r][0] += xvv * w.x;
                acc[r][1] += xvv * w.y;
                acc[r][2] += xvv * w.z;
                acc[r][3] += xvv * w.w;
            }
        }
    }
#pragma unroll
    for (int r = 0; r < 8; r++) {
        float4 v = make_float4(acc[r][0], acc[r][1], acc[r][2], acc[r][3]);
        *(float4*)&O[(size_t)(rowbase + rb + r) * 128 + c4] = v;
    }
}

// ---------------- CSR build: one block per graph ----------------
// csr_src: LOCAL src indices grouped by local dst. rowptr: LOCAL offsets.
__global__ __launch_bounds__(256) void csr_build(
    const int* __restrict__ esrc, const int* __restrict__ edst,
    int* __restrict__ csr_src, int* __restrict__ rowptr,
    int* __restrict__ degs, float* __restrict__ invdeg)
{
    __shared__ int cnt[NPG];
    __shared__ int off[NPG];
    __shared__ int cur[NPG];
    const int g = blockIdx.x, tid = threadIdx.x;
    const int ebase = g * EPG, nodebase = g * NPG;
    for (int i = tid; i < NPG; i += 256) cnt[i] = 0;
    __syncthreads();
    for (int e = tid; e < EPG; e += 256)
        atomicAdd(&cnt[edst[ebase + e] - nodebase], 1);
    __syncthreads();
    if (tid == 0) {
        int run = 0;
        for (int i = 0; i < NPG; i++) { off[i] = run; run += cnt[i]; }
    }
    __syncthreads();
    for (int i = tid; i < NPG; i += 256) {
        cur[i] = off[i];
        rowptr[nodebase + i] = off[i];
        degs[nodebase + i] = cnt[i];
        invdeg[nodebase + i] = 1.f / fmaxf((float)cnt[i], 1.f);
    }
    __syncthreads();
    for (int e = tid; e < EPG; e += 256) {
        int ld = edst[ebase + e] - nodebase;
        int p = atomicAdd(&cur[ld], 1);
        csr_src[ebase + p] = esrc[ebase + e] - nodebase;  // local src
    }
}

// ---------------- fused per-graph aggregate+combine (LDS-staged) ----------------
// A[N,128]: cols 0..63 = y = h@Wl, cols 64..127 = z = h@Wr.
// out = relu(sum_in(y[src])*invdeg + b + z) (+ resid). One block per graph.
__global__ __launch_bounds__(1024) void agg_lds(
    const float* __restrict__ A,
    const int* __restrict__ csr_src, const int* __restrict__ rowptr,
    const int* __restrict__ degs, const float* __restrict__ invdeg,
    const float* __restrict__ bias,
    const float* __restrict__ resid, int rescol,
    float* __restrict__ Xout, int outcol)
{
    __shared__ float y[NPG * 64];     // 102400 B
    __shared__ int   csr_l[EPG];      // 25600 B
    const int g = blockIdx.x, tid = threadIdx.x;
    const int ebase = g * EPG, nodebase = g * NPG;

    // stage y (cols 0..63 of A rows) coalesced: 16 float4 per row
    for (int idx = tid; idx < NPG * 16; idx += 1024) {
        int node = idx >> 4, c4 = (idx & 15) * 4;
        *(float4*)&y[node * 64 + c4] =
            *(const float4*)&A[(size_t)(nodebase + node) * 128 + c4];
    }
    // stage csr slice
    for (int e = tid; e < EPG; e += 1024) csr_l[e] = csr_src[ebase + e];
    __syncthreads();

    const int wave = tid >> 6, lane = tid & 63;
    for (int node = wave; node < NPG; node += 16) {
        const int start = rowptr[nodebase + node];
        const int dg = degs[nodebase + node];
        float acc = 0.f;
        int j = 0;
        for (; j + 4 <= dg; j += 4) {
            int s0 = csr_l[start + j];
            int s1 = csr_l[start + j + 1];
            int s2 = csr_l[start + j + 2];
            int s3 = csr_l[start + j + 3];
            acc += y[s0 * 64 + lane] + y[s1 * 64 + lane]
                 + y[s2 * 64 + lane] + y[s3 * 64 + lane];
        }
        for (; j < dg; j++) acc += y[csr_l[start + j] * 64 + lane];

        float v = acc * invdeg[nodebase + node] + bias[lane]
                + A[(size_t)(nodebase + node) * 128 + 64 + lane];
        v = fmaxf(v, 0.f);
        if (resid) v += resid[(size_t)(nodebase + node) * 128 + rescol + lane];
        Xout[(size_t)(nodebase + node) * 128 + outcol + lane] = v;
    }
}

// ---------------- per-graph score + top-k + pool + classifier ----------------
__global__ __launch_bounds__(256) void score_pool(
    const float* __restrict__ X3, int x3col,       // stride 128
    const int* __restrict__ esrc, const int* __restrict__ edst,
    const float* __restrict__ Wpr, const float* __restrict__ bpr,
    const float* __restrict__ Wpo,
    const float* __restrict__ Wlin, const float* __restrict__ blin,
    float* __restrict__ out)
{
    __shared__ float t0[NPG], s[NPG], w[NPG];
    __shared__ float wpr[64], wpo[64];
    __shared__ float pp[4 * 64];
    __shared__ float pooled[64];
    __shared__ float lg[2];
    const int g = blockIdx.x, tid = threadIdx.x;
    if (tid < 64) { wpr[tid] = Wpr[tid]; wpo[tid] = Wpo[tid]; }
    __syncthreads();

    const int nodebase = g * NPG;
    for (int i = tid; i < NPG; i += 256) {
        const float* xr = &X3[(size_t)(nodebase + i) * 128 + x3col];
        float a0 = 0.f, a1 = 0.f;
        for (int d = 0; d < 64; d++) { float x = xr[d]; a0 += x * wpr[d]; a1 += x * wpo[d]; }
        t0[i] = a0;
        s[i] = bpr[0] + a1;
    }
    __syncthreads();
    const int ebase = g * EPG;
    for (int e = tid; e < EPG; e += 256) {
        int ls = esrc[ebase + e] - nodebase;
        int ld = edst[ebase + e] - nodebase;
        atomicAdd(&s[ld], t0[ls]);
    }
    __syncthreads();
    // stable top-k selection by counting (matches lax.top_k tie-breaking)
    for (int i = tid; i < NPG; i += 256) {
        float si = s[i];
        int cnt = 0;
        for (int j = 0; j < NPG; j++) {
            float sj = s[j];
            cnt += (sj > si) || (sj == si && j < i);
        }
        w[i] = (cnt < KSEL) ? tanhf(si) * (1.f / KSEL) : 0.f;
    }
    __syncthreads();
    const int d = tid & 63, part = tid >> 6;
    float acc = 0.f;
    for (int i = part * 100; i < part * 100 + 100; i++)
        acc += w[i] * X3[(size_t)(nodebase + i) * 128 + x3col + d];
    pp[part * 64 + d] = acc;
    __syncthreads();
    if (tid < 64) pooled[tid] = pp[tid] + pp[64 + tid] + pp[128 + tid] + pp[192 + tid];
    __syncthreads();
    if (tid < 2) {
        float l = blin[tid];
        for (int dd = 0; dd < 64; dd++) l += pooled[dd] * Wlin[dd * 2 + tid];
        lg[tid] = l;
    }
    __syncthreads();
    if (tid < 2) {
        float m = fmaxf(lg[0], lg[1]);
        float lse = m + logf(expf(lg[0] - m) + expf(lg[1] - m));
        out[g * 2 + tid] = lg[tid] - lse;
    }
}

extern "C" void kernel_launch(void* const* d_in, const int* in_sizes, int n_in,
                              void* d_out, int out_size, void* d_ws, size_t ws_size,
                              hipStream_t stream) {
    const float* x    = (const float*)d_in[0];
    const int*   eidx = (const int*)d_in[1];
    const float* W1l  = (const float*)d_in[3];
    const float* W1r  = (const float*)d_in[4];
    const float* b1   = (const float*)d_in[5];
    const float* W2l  = (const float*)d_in[6];
    const float* W2r  = (const float*)d_in[7];
    const float* b2   = (const float*)d_in[8];
    const float* W3l  = (const float*)d_in[9];
    const float* W3r  = (const float*)d_in[10];
    const float* b3   = (const float*)d_in[11];
    const float* Wpr  = (const float*)d_in[12];
    const float* bpr  = (const float*)d_in[13];
    const float* Wpo  = (const float*)d_in[14];
    const float* Wlin = (const float*)d_in[15];
    const float* blin = (const float*)d_in[16];

    const int N = in_sizes[0] / F_IN;       // 204800
    const int E = in_sizes[1] / 2;          // 3276800
    const int B = N / NPG;                  // 512
    const int* esrc = eidx;
    const int* edst = eidx + E;

    float* ws = (float*)d_ws;
    float* A      = ws;                                  // [N,128] yz buffer
    float* Bb     = A + (size_t)N * 128;                 // [N,128] activations (col halves)
    float* invdeg = Bb + (size_t)N * 128;                // [N]
    float* Wc1    = invdeg + N;                          // [200,128]
    float* Wc2    = Wc1 + 200 * 128;                     // [64,128]
    float* Wc3    = Wc2 + 64 * 128;                      // [64,128]
    int*   csr    = (int*)(Wc3 + 64 * 128);              // [E] local src by dst
    int*   rowptr = csr + E;                             // [N] local offsets
    int*   degs   = rowptr + N;                          // [N]

    pack_w<<<(200 * 128 + 255) / 256, 256, 0, stream>>>(W1l, W1r, Wc1, 200);
    pack_w<<<(64 * 128 + 255) / 256, 256, 0, stream>>>(W2l, W2r, Wc2, 64);
    pack_w<<<(64 * 128 + 255) / 256, 256, 0, stream>>>(W3l, W3r, Wc3, 64);

    // CSR once (shared by all 3 layers)
    csr_build<<<B, 256, 0, stream>>>(esrc, edst, csr, rowptr, degs, invdeg);

    // layer 1: yz = x @ [W1l|W1r]; x1 -> Bb cols 0..63
    gemm128<200><<<N / 64, 256, 0, stream>>>(x, F_IN, Wc1, A);
    agg_lds<<<B, 1024, 0, stream>>>(A, csr, rowptr, degs, invdeg, b1,
                                    nullptr, 0, Bb, 0);

    // layer 2: yz = x1 @ [W2l|W2r]; x2 = relu(...)+x1 -> Bb cols 64..127
    gemm128<64><<<N / 64, 256, 0, stream>>>(Bb, 128, Wc2, A);
    agg_lds<<<B, 1024, 0, stream>>>(A, csr, rowptr, degs, invdeg, b2,
                                    Bb, 0, Bb, 64);

    // layer 3: yz = x2 @ [W3l|W3r]; x3 = relu(...)+x2 -> Bb cols 0..63
    gemm128<64><<<N / 64, 256, 0, stream>>>(Bb + 64, 128, Wc3, A);
    agg_lds<<<B, 1024, 0, stream>>>(A, csr, rowptr, degs, invdeg, b3,
                                    Bb, 64, Bb, 0);

    // score + top-k + pool + classifier
    score_pool<<<B, 256, 0, stream>>>(Bb, 0, esrc, edst, Wpr, bpr, Wpo, Wlin, blin,
                                      (float*)d_out);
}

// Round 4
// 609.706 us; speedup vs baseline: 6.3894x; 1.0685x over previous
//
#include <hip/hip_runtime.h>
#include <hip/hip_bf16.h>
#include <math.h>

#define F_IN 200
#define HDIM 64
#define NPG  400
#define EPG  6400
#define KSEL 200   // NPG/2

// ---------------- pack [K,64]|[K,64] -> [K,128] ----------------
__global__ void pack_w(const float* __restrict__ Wl, const float* __restrict__ Wr,
                       float* __restrict__ Wc, int K) {
    int i = blockIdx.x * blockDim.x + threadIdx.x;
    if (i >= K * 128) return;
    int k = i >> 7, c = i & 127;
    Wc[i] = (c < 64) ? Wl[k * 64 + c] : Wr[k * 64 + (c - 64)];
}

// ---------------- tiled GEMM: O[N,128] = X[N,K] @ W[K,128] ----------------
// 128x128 tile, BK=8, 256 threads, double-buffered LDS for X (K-major) and W.
// Thread (tid) owns rows {r0..r0+3, r0+64..r0+67}, cols {c0..c0+3, c0+64..c0+67}.
template <int K>
__global__ __launch_bounds__(256) void gemm_tile(const float* __restrict__ X, int ldx,
                                                 const float* __restrict__ W,
                                                 float* __restrict__ O) {
    constexpr int NCH = K / 8;
    __shared__ float Xs[2][8][128];
    __shared__ float Ws[2][8][128];
    const int tid = threadIdx.x;
    const size_t rowbase = (size_t)blockIdx.x * 128;

    const int sr = tid >> 1;            // staging: row 0..127
    const int sq = (tid & 1) * 4;       // staging: k sub-offset 0|4
    const int wr = tid >> 5;            // staging W: k-row 0..7
    const int wc = (tid & 31) * 4;      // staging W: col

    const int c0 = (tid & 15) * 4;
    const int r0 = (tid >> 4) * 4;

    float acc[2][2][4][4];
#pragma unroll
    for (int a = 0; a < 2; a++)
#pragma unroll
        for (int b = 0; b < 2; b++)
#pragma unroll
            for (int i = 0; i < 4; i++)
#pragma unroll
                for (int j = 0; j < 4; j++) acc[a][b][i][j] = 0.f;

#define STAGE(bf, kc_) {                                                        \
        float4 xv = *(const float4*)&X[(rowbase + sr) * (size_t)ldx + (kc_) + sq]; \
        Xs[bf][sq + 0][sr] = xv.x; Xs[bf][sq + 1][sr] = xv.y;                   \
        Xs[bf][sq + 2][sr] = xv.z; Xs[bf][sq + 3][sr] = xv.w;                   \
        *(float4*)&Ws[bf][wr][wc] = *(const float4*)&W[(size_t)((kc_) + wr) * 128 + wc]; \
    }

    STAGE(0, 0);
    __syncthreads();
    for (int c = 0; c < NCH; c++) {
        const int cur = c & 1;
        if (c + 1 < NCH) STAGE(cur ^ 1, (c + 1) * 8);
#pragma unroll
        for (int k = 0; k < 8; k++) {
            float4 xa = *(const float4*)&Xs[cur][k][r0];
            float4 xb = *(const float4*)&Xs[cur][k][r0 + 64];
            float4 wa = *(const float4*)&Ws[cur][k][c0];
            float4 wb = *(const float4*)&Ws[cur][k][c0 + 64];
            const float xs0[4] = {xa.x, xa.y, xa.z, xa.w};
            const float xs1[4] = {xb.x, xb.y, xb.z, xb.w};
            const float ws0[4] = {wa.x, wa.y, wa.z, wa.w};
            const float ws1[4] = {wb.x, wb.y, wb.z, wb.w};
#pragma unroll
            for (int i = 0; i < 4; i++)
#pragma unroll
                for (int j = 0; j < 4; j++) {
                    acc[0][0][i][j] += xs0[i] * ws0[j];
                    acc[0][1][i][j] += xs0[i] * ws1[j];
                    acc[1][0][i][j] += xs1[i] * ws0[j];
                    acc[1][1][i][j] += xs1[i] * ws1[j];
                }
        }
        __syncthreads();
    }
#undef STAGE

#pragma unroll
    for (int a = 0; a < 2; a++)
#pragma unroll
        for (int i = 0; i < 4; i++) {
            size_t row = rowbase + r0 + a * 64 + i;
#pragma unroll
            for (int b = 0; b < 2; b++) {
                float4 v = make_float4(acc[a][b][i][0], acc[a][b][i][1],
                                       acc[a][b][i][2], acc[a][b][i][3]);
                *(float4*)&O[row * 128 + c0 + b * 64] = v;
            }
        }
}

// ---------------- CSR build: one block per graph ----------------
// csr_src: LOCAL src indices grouped by local dst. rowptr: LOCAL offsets.
__global__ __launch_bounds__(256) void csr_build(
    const int* __restrict__ esrc, const int* __restrict__ edst,
    int* __restrict__ csr_src, int* __restrict__ rowptr,
    int* __restrict__ degs, float* __restrict__ invdeg)
{
    __shared__ int cnt[NPG];
    __shared__ int off[NPG];
    __shared__ int cur[NPG];
    const int g = blockIdx.x, tid = threadIdx.x;
    const int ebase = g * EPG, nodebase = g * NPG;
    for (int i = tid; i < NPG; i += 256) cnt[i] = 0;
    __syncthreads();
    for (int e = tid; e < EPG; e += 256)
        atomicAdd(&cnt[edst[ebase + e] - nodebase], 1);
    __syncthreads();
    if (tid == 0) {
        int run = 0;
        for (int i = 0; i < NPG; i++) { off[i] = run; run += cnt[i]; }
    }
    __syncthreads();
    for (int i = tid; i < NPG; i += 256) {
        cur[i] = off[i];
        rowptr[nodebase + i] = off[i];
        degs[nodebase + i] = cnt[i];
        invdeg[nodebase + i] = 1.f / fmaxf((float)cnt[i], 1.f);
    }
    __syncthreads();
    for (int e = tid; e < EPG; e += 256) {
        int ld = edst[ebase + e] - nodebase;
        int p = atomicAdd(&cur[ld], 1);
        csr_src[ebase + p] = esrc[ebase + e] - nodebase;  // local src
    }
}

// ---------------- fused per-graph aggregate+combine (LDS-staged) ----------------
// A[N,128]: cols 0..63 = y = h@Wl, cols 64..127 = z = h@Wr.
// out = relu(sum_in(y[src])*invdeg + b + z) (+ resid). One block per graph.
// resid/Xout are compact [N,64].
__global__ __launch_bounds__(1024) void agg_lds(
    const float* __restrict__ A,
    const int* __restrict__ csr_src, const int* __restrict__ rowptr,
    const int* __restrict__ degs, const float* __restrict__ invdeg,
    const float* __restrict__ bias,
    const float* __restrict__ resid,
    float* __restrict__ Xout)
{
    __shared__ float y[NPG * 64];     // 102400 B
    __shared__ int   csr_l[EPG];      // 25600 B
    const int g = blockIdx.x, tid = threadIdx.x;
    const int ebase = g * EPG, nodebase = g * NPG;

    for (int idx = tid; idx < NPG * 16; idx += 1024) {
        int node = idx >> 4, c4 = (idx & 15) * 4;
        *(float4*)&y[node * 64 + c4] =
            *(const float4*)&A[(size_t)(nodebase + node) * 128 + c4];
    }
    for (int e = tid; e < EPG; e += 1024) csr_l[e] = csr_src[ebase + e];
    __syncthreads();

    const int wave = tid >> 6, lane = tid & 63;
    for (int node = wave; node < NPG; node += 16) {
        const int start = rowptr[nodebase + node];
        const int dg = degs[nodebase + node];
        float acc = 0.f;
        int j = 0;
        for (; j + 4 <= dg; j += 4) {
            int s0 = csr_l[start + j];
            int s1 = csr_l[start + j + 1];
            int s2 = csr_l[start + j + 2];
            int s3 = csr_l[start + j + 3];
            acc += y[s0 * 64 + lane] + y[s1 * 64 + lane]
                 + y[s2 * 64 + lane] + y[s3 * 64 + lane];
        }
        for (; j < dg; j++) acc += y[csr_l[start + j] * 64 + lane];

        float v = acc * invdeg[nodebase + node] + bias[lane]
                + A[(size_t)(nodebase + node) * 128 + 64 + lane];
        v = fmaxf(v, 0.f);
        if (resid) v += resid[(size_t)(nodebase + node) * 64 + lane];
        Xout[(size_t)(nodebase + node) * 64 + lane] = v;
    }
}

// ---------------- per-graph score + top-k + pool + classifier ----------------
// X3 compact [N,64]
__global__ __launch_bounds__(256) void score_pool(
    const float* __restrict__ X3,
    const int* __restrict__ esrc, const int* __restrict__ edst,
    const float* __restrict__ Wpr, const float* __restrict__ bpr,
    const float* __restrict__ Wpo,
    const float* __restrict__ Wlin, const float* __restrict__ blin,
    float* __restrict__ out)
{
    __shared__ float t0[NPG], s[NPG], w[NPG];
    __shared__ float wpr[64], wpo[64];
    __shared__ float pp[4 * 64];
    __shared__ float pooled[64];
    __shared__ float lg[2];
    const int g = blockIdx.x, tid = threadIdx.x;
    if (tid < 64) { wpr[tid] = Wpr[tid]; wpo[tid] = Wpo[tid]; }
    __syncthreads();

    const int nodebase = g * NPG;
    for (int i = tid; i < NPG; i += 256) {
        const float* xr = &X3[(size_t)(nodebase + i) * 64];
        float a0 = 0.f, a1 = 0.f;
        for (int d = 0; d < 64; d++) { float x = xr[d]; a0 += x * wpr[d]; a1 += x * wpo[d]; }
        t0[i] = a0;
        s[i] = bpr[0] + a1;
    }
    __syncthreads();
    const int ebase = g * EPG;
    for (int e = tid; e < EPG; e += 256) {
        int ls = esrc[ebase + e] - nodebase;
        int ld = edst[ebase + e] - nodebase;
        atomicAdd(&s[ld], t0[ls]);
    }
    __syncthreads();
    // stable top-k selection by counting (matches lax.top_k tie-breaking)
    for (int i = tid; i < NPG; i += 256) {
        float si = s[i];
        int cnt = 0;
        for (int j = 0; j < NPG; j++) {
            float sj = s[j];
            cnt += (sj > si) || (sj == si && j < i);
        }
        w[i] = (cnt < KSEL) ? tanhf(si) * (1.f / KSEL) : 0.f;
    }
    __syncthreads();
    const int d = tid & 63, part = tid >> 6;
    float acc = 0.f;
    for (int i = part * 100; i < part * 100 + 100; i++)
        acc += w[i] * X3[(size_t)(nodebase + i) * 64 + d];
    pp[part * 64 + d] = acc;
    __syncthreads();
    if (tid < 64) pooled[tid] = pp[tid] + pp[64 + tid] + pp[128 + tid] + pp[192 + tid];
    __syncthreads();
    if (tid < 2) {
        float l = blin[tid];
        for (int dd = 0; dd < 64; dd++) l += pooled[dd] * Wlin[dd * 2 + tid];
        lg[tid] = l;
    }
    __syncthreads();
    if (tid < 2) {
        float m = fmaxf(lg[0], lg[1]);
        float lse = m + logf(expf(lg[0] - m) + expf(lg[1] - m));
        out[g * 2 + tid] = lg[tid] - lse;
    }
}

extern "C" void kernel_launch(void* const* d_in, const int* in_sizes, int n_in,
                              void* d_out, int out_size, void* d_ws, size_t ws_size,
                              hipStream_t stream) {
    const float* x    = (const float*)d_in[0];
    const int*   eidx = (const int*)d_in[1];
    const float* W1l  = (const float*)d_in[3];
    const float* W1r  = (const float*)d_in[4];
    const float* b1   = (const float*)d_in[5];
    const float* W2l  = (const float*)d_in[6];
    const float* W2r  = (const float*)d_in[7];
    const float* b2   = (const float*)d_in[8];
    const float* W3l  = (const float*)d_in[9];
    const float* W3r  = (const float*)d_in[10];
    const float* b3   = (const float*)d_in[11];
    const float* Wpr  = (const float*)d_in[12];
    const float* bpr  = (const float*)d_in[13];
    const float* Wpo  = (const float*)d_in[14];
    const float* Wlin = (const float*)d_in[15];
    const float* blin = (const float*)d_in[16];

    const int N = in_sizes[0] / F_IN;       // 204800
    const int E = in_sizes[1] / 2;          // 3276800
    const int B = N / NPG;                  // 512
    const int* esrc = eidx;
    const int* edst = eidx + E;

    float* ws = (float*)d_ws;
    float* A      = ws;                                  // [N,128] yz buffer
    float* P0     = A + (size_t)N * 128;                 // [N,64] compact acts
    float* P1     = P0 + (size_t)N * 64;                 // [N,64] compact acts
    float* invdeg = P1 + (size_t)N * 64;                 // [N]
    float* Wc1    = invdeg + N;                          // [200,128]
    float* Wc2    = Wc1 + 200 * 128;                     // [64,128]
    float* Wc3    = Wc2 + 64 * 128;                      // [64,128]
    int*   csr    = (int*)(Wc3 + 64 * 128);              // [E] local src by dst
    int*   rowptr = csr + E;                             // [N] local offsets
    int*   degs   = rowptr + N;                          // [N]

    pack_w<<<(200 * 128 + 255) / 256, 256, 0, stream>>>(W1l, W1r, Wc1, 200);
    pack_w<<<(64 * 128 + 255) / 256, 256, 0, stream>>>(W2l, W2r, Wc2, 64);
    pack_w<<<(64 * 128 + 255) / 256, 256, 0, stream>>>(W3l, W3r, Wc3, 64);

    // CSR once (shared by all 3 layers)
    csr_build<<<B, 256, 0, stream>>>(esrc, edst, csr, rowptr, degs, invdeg);

    // layer 1: yz = x @ [W1l|W1r]; x1 -> P0
    gemm_tile<200><<<N / 128, 256, 0, stream>>>(x, F_IN, Wc1, A);
    agg_lds<<<B, 1024, 0, stream>>>(A, csr, rowptr, degs, invdeg, b1, nullptr, P0);

    // layer 2: yz = x1 @ [W2l|W2r]; x2 = relu(...)+x1 -> P1
    gemm_tile<64><<<N / 128, 256, 0, stream>>>(P0, 64, Wc2, A);
    agg_lds<<<B, 1024, 0, stream>>>(A, csr, rowptr, degs, invdeg, b2, P0, P1);

    // layer 3: yz = x2 @ [W3l|W3r]; x3 = relu(...)+x2 -> P0 (x1 dead)
    gemm_tile<64><<<N / 128, 256, 0, stream>>>(P1, 64, Wc3, A);
    agg_lds<<<B, 1024, 0, stream>>>(A, csr, rowptr, degs, invdeg, b3, P1, P0);

    // score + top-k + pool + classifier
    score_pool<<<B, 256, 0, stream>>>(P0, esrc, edst, Wpr, bpr, Wpo, Wlin, blin,
                                      (float*)d_out);
}